// Round 1
// 9.673 us; speedup vs baseline: 1.3472x; 1.3472x over previous
//
#include <hip/hip_runtime.h>

// MultigridLayer2: exact per-node 5x5 block-Jacobi for (AtA + alpha I) x = b,
// now with 2x2 overlapping domain decomposition (R4).
//
// Algebra (unchanged from R3): with Bi = exact inverse of the node-diagonal
// 5x5 block D, the iteration x_new = Bi*b - W*Bi*t(x) (t = neighbor-only
// coupling from the derivative rows, weight W = 1/DS = 1e-3) converges with
// rho <= ||D^-1||inf * ||C||inf <= (sqrt(5)/alpha) * 4W(2+h) <= 0.184
// (RIGOROUS: D = alpha*I + c c^T + PSD coupling => lambda_min >= alpha).
// Truncation after x1=Bi*b + 5 steps <= 0.184^6 * ||x|| ~ 3e-5*||x||
// — negligible vs the fp32-reference absmax floor (~0.06) and threshold.
//
// Decomposition (R4): the monolithic version used 4 blocks => 4/256 CUs,
// latency-bound at 13 us. Each Jacobi application shrinks the valid region
// by one ring, so a tile with halo width = STEPS reproduces the monolithic
// result exactly on its owned interior with NO inter-block communication.
// STEPS = HALO = 5; tiles = 2x2 quadrants of 16x16 owned + 5 halo =
// 21x21 = 441 threads (7 waves). Grid = 4 batches x 4 quadrants = 16 blocks.
// x1 = Bi*b is exact everywhere in the tile (purely local), so after 5
// steps rows/cols within distance 5 of a cut edge are garbage-but-finite
// (iteration is a contraction, values stay bounded) and are simply not
// written back.

#define G_ 1024
#define K_ 5
#define T_ 21          // tile extent: 16 owned + 5 halo
#define STEPS_ 5       // Jacobi applications after x1 = Bi*b (== halo width)

__global__ __launch_bounds__(441) void mg_solve(
    const float* __restrict__ coeffs,
    const float* __restrict__ rhs,
    const float* __restrict__ iv_rhs,
    const float* __restrict__ steps0,
    const float* __restrict__ steps1,
    float* __restrict__ out)
{
    constexpr float ALPHA = 0.1f;
    constexpr float W = 1.0f / 1000.0f;   // Pinv on derivative rows

    __shared__ float xs[2][T_ * T_ * K_];  // 2 * 2205 * 4 B = 17.6 KB

    const int l1 = threadIdx.x;            // tile-local coord1 (fast)
    const int l0 = threadIdx.y;            // tile-local coord0
    const int bb = blockIdx.x >> 2;        // batch
    const int q0 = (blockIdx.x >> 1) & 1;  // quadrant along coord0
    const int q1 = blockIdx.x & 1;         // quadrant along coord1
    const int i0 = q0 * (32 - T_) + l0;    // global node coords (tile origin 0 or 11)
    const int i1 = q1 * (32 - T_) + l1;
    const int g  = i0 * 32 + i1;           // global node id
    const int n  = l0 * T_ + l1;           // tile-local node id

    // ---- load per-node data ----
    float c0[K_], bvec[K_];
    {
        const float rb = rhs[bb * G_ + g];
#pragma unroll
        for (int k = 0; k < K_; ++k) {
            c0[k]  = coeffs[g * K_ + k];                   // batch 0 (defines M)
            bvec[k] = coeffs[(bb * G_ + g) * K_ + k] * rb; // b = A_b^T Pinv A_rhs
        }
        if (i0 == 0) bvec[0] += iv_rhs[bb * 32 + i1];
    }

    const bool m0 = (i0 > 0), p0 = (i0 < 31), m1 = (i1 > 0), p1 = (i1 < 31);
    const float h0m = m0 ? steps0[i0 - 1] : 0.f;   // batch-0 steps (only ones used)
    const float h0p = p0 ? steps0[i0]     : 0.f;
    const float h1m = m1 ? steps1[i1 - 1] : 0.f;
    const float h1p = p1 ? steps1[i1]     : 0.f;

    // ---- exact 5x5 diagonal block of M (batch 0) ----
    float D[K_][K_];
#pragma unroll
    for (int j = 0; j < K_; ++j)
#pragma unroll
        for (int k = 0; k < K_; ++k)
            D[j][k] = c0[j] * c0[k] + ((j == k) ? ALPHA : 0.f);
    if (i0 == 0) D[0][0] += 1.f;   // initial-condition row

    auto addp = [&](int s, int d, float hm, float hp, bool hasm, bool hasp) {
        if (hasm) { D[s][s] += 2.f * W; D[s][d] -= W * hm; D[d][s] -= W * hm; D[d][d] += W * hm * hm; }
        if (hasp) { D[s][s] += 2.f * W; D[s][d] += W * hp; D[d][s] += W * hp; D[d][d] += W * hp * hp; }
    };
    addp(0, 1, h0m, h0p, m0, p0);
    addp(0, 2, h1m, h1p, m1, p1);
    addp(1, 3, h0m, h0p, m0, p0);
    addp(2, 4, h1m, h1p, m1, p1);

    // ---- invert D (Gauss-Jordan, SPD, pivots >= alpha = 0.1) ----
    float Bi[K_][K_];
#pragma unroll
    for (int j = 0; j < K_; ++j)
#pragma unroll
        for (int k = 0; k < K_; ++k) Bi[j][k] = (j == k) ? 1.f : 0.f;
#pragma unroll
    for (int p = 0; p < K_; ++p) {
        const float piv = 1.f / D[p][p];
#pragma unroll
        for (int k = 0; k < K_; ++k) { D[p][k] *= piv; Bi[p][k] *= piv; }
#pragma unroll
        for (int r = 0; r < K_; ++r) {
            if (r == p) continue;
            const float f = D[r][p];
#pragma unroll
            for (int k = 0; k < K_; ++k) { D[r][k] -= f * D[p][k]; Bi[r][k] -= f * Bi[p][k]; }
        }
    }

    // ---- precompute Bib = Bi*b and nBiW = -W*Bi ----
    float Bib[K_];
#pragma unroll
    for (int k = 0; k < K_; ++k) {
        float a = 0.f;
#pragma unroll
        for (int j = 0; j < K_; ++j) a += Bi[k][j] * bvec[j];
        Bib[k] = a;
    }
#pragma unroll
    for (int k = 0; k < K_; ++k)
#pragma unroll
        for (int j = 0; j < K_; ++j) Bi[k][j] *= -W;   // Bi is now nBiW

    // block-local neighbor availability (global flag AND in-tile)
    const bool lm0 = m0 && (l0 > 0);
    const bool lp0 = p0 && (l0 < T_ - 1);
    const bool lm1 = m1 && (l1 > 0);
    const bool lp1 = p1 && (l1 < T_ - 1);

    // ---- x1 = Bi*b (exact everywhere in tile, incl. halo) ----
#pragma unroll
    for (int k = 0; k < K_; ++k) xs[0][n * K_ + k] = Bib[k];
    __syncthreads();

    // ---- Jacobi: x_new = Bib + nBiW * t(x),  t = neighbor coupling / W ----
    float xn[K_];
    for (int it = 0; it < STEPS_; ++it) {
        const float* __restrict__ xr = xs[it & 1];

        float t0 = 0.f, t1 = 0.f, t2 = 0.f, t3 = 0.f, t4 = 0.f;
        if (lm0) {                              // coord0 minus neighbor (n-T_)
            const float a = xr[(n - T_) * K_ + 0];
            const float b = xr[(n - T_) * K_ + 1];
            const float d = xr[(n - T_) * K_ + 3];
            t0 -= 2.f * a + h0m * b;  t1 += h0m * a;   // pair (0,1)
            t1 -= 2.f * b + h0m * d;  t3 += h0m * b;   // pair (1,3)
        }
        if (lp0) {                              // coord0 plus neighbor (n+T_)
            const float a = xr[(n + T_) * K_ + 0];
            const float b = xr[(n + T_) * K_ + 1];
            const float d = xr[(n + T_) * K_ + 3];
            t0 -= 2.f * a - h0p * b;  t1 -= h0p * a;
            t1 -= 2.f * b - h0p * d;  t3 -= h0p * b;
        }
        if (lm1) {                              // coord1 minus neighbor (n-1)
            const float a = xr[(n - 1) * K_ + 0];
            const float b = xr[(n - 1) * K_ + 2];
            const float d = xr[(n - 1) * K_ + 4];
            t0 -= 2.f * a + h1m * b;  t2 += h1m * a;   // pair (0,2)
            t2 -= 2.f * b + h1m * d;  t4 += h1m * b;   // pair (2,4)
        }
        if (lp1) {                              // coord1 plus neighbor (n+1)
            const float a = xr[(n + 1) * K_ + 0];
            const float b = xr[(n + 1) * K_ + 2];
            const float d = xr[(n + 1) * K_ + 4];
            t0 -= 2.f * a - h1p * b;  t2 -= h1p * a;
            t2 -= 2.f * b - h1p * d;  t4 -= h1p * b;
        }

#pragma unroll
        for (int k = 0; k < K_; ++k)
            xn[k] = Bib[k] + Bi[k][0] * t0 + Bi[k][1] * t1 + Bi[k][2] * t2
                          + Bi[k][3] * t3 + Bi[k][4] * t4;

        if (it + 1 < STEPS_) {                  // last result read from registers
            float* __restrict__ xw = xs[(it + 1) & 1];
#pragma unroll
            for (int k = 0; k < K_; ++k) xw[n * K_ + k] = xn[k];
            __syncthreads();
        }
    }

    // ---- write back owned interior only (halo rings are invalid) ----
    // owned local range: l0 in [q0*5, q0*5+16), l1 in [q1*5, q1*5+16)
    if (l0 >= q0 * 5 && l0 < q0 * 5 + 16 &&
        l1 >= q1 * 5 && l1 < q1 * 5 + 16) {
        out[bb * G_ + g] = xn[0];
#pragma unroll
        for (int k = 0; k < K_; ++k)
            out[4 * G_ + (bb * G_ + g) * K_ + k] = xn[k];
    }
}

extern "C" void kernel_launch(void* const* d_in, const int* in_sizes, int n_in,
                              void* d_out, int out_size, void* d_ws, size_t ws_size,
                              hipStream_t stream) {
    const float* coeffs = (const float*)d_in[0];
    const float* rhs    = (const float*)d_in[1];
    const float* iv_rhs = (const float*)d_in[2];
    const float* steps0 = (const float*)d_in[3];
    const float* steps1 = (const float*)d_in[4];
    float* out = (float*)d_out;
    // 4 batches x 4 quadrants; 21x21 tile (16 owned + 5 halo) per block
    mg_solve<<<16, dim3(T_, T_), 0, stream>>>(coeffs, rhs, iv_rhs, steps0, steps1, out);
}